// Round 10
// baseline (268.490 us; speedup 1.0000x reference)
//
#include <hip/hip_runtime.h>
#include <hip/hip_bf16.h>

#define NTOK 8192
#define DIM 512
#define HID 1024
#define NE 16
#define CAP 1280   // per-expert capacity; mean load = 1024, sigma ~30
#define MT 20      // m-tiles per expert (CAP/64)

typedef __attribute__((ext_vector_type(8))) short short8;
typedef __attribute__((ext_vector_type(8))) unsigned short us8;
typedef __attribute__((ext_vector_type(4))) float f32x4;

static __device__ __forceinline__ unsigned short f2bf(float f) {
    __hip_bfloat16 h = __float2bfloat16(f);
    return __builtin_bit_cast(unsigned short, h);
}
static __device__ __forceinline__ float bf2f(unsigned short u) {
    unsigned int v = (unsigned int)u << 16;
    return __builtin_bit_cast(float, v);
}

// async global->LDS, 16B per lane; LDS dst = wave-uniform base + lane*16.
// NOTE (R8 lesson): never place a dependent global_load->ds_write between
// gl_lds issue and the barrier -- the forced vmcnt(0) drains the async queue.
static __device__ __forceinline__ void gl_lds16(const unsigned short* g, unsigned short* l) {
    __builtin_amdgcn_global_load_lds(
        (const __attribute__((address_space(1))) unsigned int*)g,
        (__attribute__((address_space(3))) unsigned int*)l, 16, 0, 0);
}

// tanh-approx GELU; max |err| vs exact erf-GELU ~3e-3.
static __device__ __forceinline__ float gelu_f(float v) {
    float u = v * (0.7978845608f + 0.0356774081f * v * v);
    return v / (1.0f + __expf(-2.0f * u));
}

// LDS-aggregated routing: per-block local counts, 16 global atomics/block.
__global__ __launch_bounds__(256) void route_fill(const float* __restrict__ routing,
                                                  int* __restrict__ cnt,
                                                  int* __restrict__ sidx,
                                                  float* __restrict__ wtb) {
    __shared__ int lcnt[NE], lbase[NE];
    int t = threadIdx.x;
    int n = blockIdx.x * 256 + t;
    if (t < NE) lcnt[t] = 0;
    __syncthreads();
    int mye[2]; float myw[2]; int mypos[2]; int slot = 0;
    #pragma unroll
    for (int e = 0; e < NE; e++) {
        float r = routing[n * NE + e];
        if (r != 0.0f && slot < 2) {
            mye[slot] = e; myw[slot] = r;
            mypos[slot] = atomicAdd(&lcnt[e], 1);
            slot++;
        }
    }
    __syncthreads();
    if (t < NE) lbase[t] = atomicAdd(&cnt[t], lcnt[t]);
    __syncthreads();
    for (int s = 0; s < slot; s++) {
        int e = mye[s];
        int p = lbase[e] + mypos[s];
        if (p < CAP) { sidx[e * CAP + p] = n * 2 + s; wtb[e * CAP + p] = myw[s]; }
    }
}

// prep2: one big dispatch = weight transposes (blocks 0..4095) + token gather
// (blocks 4096..9215, 4 rows each).
__global__ __launch_bounds__(256) void prep2(const float* __restrict__ W1,
                                             const float* __restrict__ W2,
                                             unsigned short* __restrict__ w1t,
                                             unsigned short* __restrict__ w2t,
                                             const float* __restrict__ x,
                                             const int* __restrict__ cnt,
                                             const int* __restrict__ sidx,
                                             unsigned short* __restrict__ xg) {
    int b = blockIdx.x;
    int t = threadIdx.x;
    if (b < 4096) {
        __shared__ float tile[64][65];
        const float* src; unsigned short* dst; int R, C, bx, by;
        if (b < 2048) {               // W1: [DIM][HID], per-e tiles 16x8
            int e = b >> 7, rem = b & 127; bx = rem & 15; by = rem >> 4;
            R = DIM; C = HID;
            src = W1 + (size_t)e * R * C; dst = w1t + (size_t)e * R * C;
        } else {                      // W2: [HID][DIM], per-e tiles 8x16
            int bb = b - 2048;
            int e = bb >> 7, rem = bb & 127; bx = rem & 7; by = rem >> 3;
            R = HID; C = DIM;
            src = W2 + (size_t)e * R * C; dst = w2t + (size_t)e * R * C;
        }
        int c0 = bx * 64, r0 = by * 64;
        int tx = t & 15, ty = t >> 4;   // 16x16
        #pragma unroll
        for (int i = 0; i < 4; i++) {
            float4 v = *(const float4*)(src + (size_t)(r0 + ty + i * 16) * C + c0 + tx * 4);
            tile[ty + i * 16][tx * 4 + 0] = v.x;
            tile[ty + i * 16][tx * 4 + 1] = v.y;
            tile[ty + i * 16][tx * 4 + 2] = v.z;
            tile[ty + i * 16][tx * 4 + 3] = v.w;
        }
        __syncthreads();
        int seg = t & 7;                // 8 output segments of 8
        #pragma unroll
        for (int i = 0; i < 2; i++) {
            int dr = (t >> 3) + i * 32; // dst row (= source col)
            us8 o;
            #pragma unroll
            for (int j = 0; j < 8; j++)
                o[j] = f2bf(tile[seg * 8 + j][dr]);
            *(us8*)(dst + (size_t)(c0 + dr) * R + r0 + seg * 8) = o;
        }
    } else {
        // gather: 4 rows/block, 64 lanes/row, 16B us8 writes
        int gi = b - 4096;              // 0..5119
        int lane = t & 63, rl = t >> 6;
        int row = gi * 4 + rl;          // 0..20479 = e*CAP + r
        int e = row / CAP, r = row - e * CAP;
        int c = cnt[e]; c = c > CAP ? CAP : c;
        us8 o;
        if (r < c) {
            int n = sidx[row] >> 1;
            const float* xr = x + (size_t)n * DIM + lane * 8;
            float4 v0 = *(const float4*)xr;
            float4 v1 = *(const float4*)(xr + 4);
            o[0] = f2bf(v0.x); o[1] = f2bf(v0.y); o[2] = f2bf(v0.z); o[3] = f2bf(v0.w);
            o[4] = f2bf(v1.x); o[5] = f2bf(v1.y); o[6] = f2bf(v1.z); o[7] = f2bf(v1.w);
        } else {
            #pragma unroll
            for (int j = 0; j < 8; j++) o[j] = 0;
        }
        *(us8*)(xg + (size_t)row * DIM + lane * 8) = o;
    }
}

// 64x128 tile, BK=64, 4 waves (2x2): wave covers 32 rows x 64 cols,
// each wave 2x4 of 16x16x32 bf16 MFMA. A: MxK row-major, B: NxK row-major.
template <int K>
__device__ __forceinline__ void mfma_main64(const unsigned short* __restrict__ A,
                                            const unsigned short* __restrict__ B,
                                            unsigned short* As, unsigned short* Bs,
                                            f32x4 acc[2][4]) {
    int t = threadIdx.x;
    int wave = t >> 6, lane = t & 63;
    int wm = wave >> 1, wn = wave & 1;
    int quad = lane >> 4, l16 = lane & 15;
    int lr = lane >> 3;
    int col = (lane & 7) << 3;
    for (int kc = 0; kc < K; kc += 64) {
        __syncthreads();
        #pragma unroll
        for (int j = 0; j < 2; j++) {       // A: 64 rows
            int rb = wave * 16 + j * 8;
            gl_lds16(A + (size_t)(rb + lr) * K + kc + col, As + rb * 64);
        }
        #pragma unroll
        for (int j = 0; j < 4; j++) {       // B: 128 rows
            int rb = wave * 32 + j * 8;
            gl_lds16(B + (size_t)(rb + lr) * K + kc + col, Bs + rb * 64);
        }
        __syncthreads();
        #pragma unroll
        for (int kk = 0; kk < 64; kk += 32) {
            short8 av[2], bv[4];
            #pragma unroll
            for (int mt = 0; mt < 2; mt++)
                av[mt] = *(const short8*)(&As[(wm * 32 + mt * 16 + l16) * 64 + kk + quad * 8]);
            #pragma unroll
            for (int nt = 0; nt < 4; nt++)
                bv[nt] = *(const short8*)(&Bs[(wn * 64 + nt * 16 + l16) * 64 + kk + quad * 8]);
            #pragma unroll
            for (int mt = 0; mt < 2; mt++)
                #pragma unroll
                for (int nt = 0; nt < 4; nt++)
                    acc[mt][nt] = __builtin_amdgcn_mfma_f32_16x16x32_bf16(
                        av[mt], bv[nt], acc[mt][nt], 0, 0, 0);
        }
    }
}

// R5 swizzle (proven): all NT n-blocks of one (e,m) A-panel get flat ids
// congruent mod 8 -> A-sharers co-located per XCD; A fetched ~once/XCD.
// (Hard expert->XCD pinning regressed: L2 capacity thrash tripled WRITE_SIZE.)

__global__ __launch_bounds__(256, 6) void gemm1_gelu(
    const unsigned short* __restrict__ xg, const unsigned short* __restrict__ w1t,
    const float* __restrict__ b1, const int* __restrict__ cnt,
    unsigned short* __restrict__ hbuf) {
    __shared__ __align__(16) unsigned short As[64 * 64];
    __shared__ __align__(16) unsigned short Bs[128 * 64];
    int L = blockIdx.x;                      // 2560, NT=8
    int cc = L & 7, n = (L >> 3) & 7, g = L >> 6;
    int pi = cc + (g << 3);                  // [0,320)
    int e = pi / MT, m = pi % MT;
    int c = cnt[e]; c = c > CAP ? CAP : c;
    int m0 = m * 64;
    if (m0 >= c) return;
    int n0 = n * 128;
    const unsigned short* A = xg + ((size_t)e * CAP + m0) * DIM;
    const unsigned short* B = w1t + ((size_t)e * HID + n0) * DIM;
    f32x4 z = {0.f, 0.f, 0.f, 0.f};
    f32x4 acc[2][4];
    #pragma unroll
    for (int mt = 0; mt < 2; mt++)
        #pragma unroll
        for (int nt = 0; nt < 4; nt++) acc[mt][nt] = z;
    mfma_main64<DIM>(A, B, As, Bs, acc);
    int t = threadIdx.x;
    int wave = t >> 6, lane = t & 63;
    int wm = wave >> 1, wn = wave & 1, quad = lane >> 4, l16 = lane & 15;
    #pragma unroll
    for (int nt = 0; nt < 4; nt++) {
        int gn = n0 + wn * 64 + nt * 16 + l16;
        float bias = b1[e * HID + gn];
        #pragma unroll
        for (int mt = 0; mt < 2; mt++) {
            #pragma unroll
            for (int r = 0; r < 4; r++) {
                int gm = m0 + wm * 32 + mt * 16 + quad * 4 + r;
                float v = acc[mt][nt][r] + bias;
                hbuf[((size_t)e * CAP + gm) * HID + gn] = f2bf(gelu_f(v));
            }
        }
    }
}

__global__ __launch_bounds__(256, 6) void gemm2_store(
    const unsigned short* __restrict__ hbuf, const unsigned short* __restrict__ w2t,
    const float* __restrict__ b2, const int* __restrict__ cnt,
    const int* __restrict__ sidx, const float* __restrict__ wtb,
    unsigned short* __restrict__ ybuf) {
    __shared__ __align__(16) unsigned short As[64 * 64];
    __shared__ __align__(16) unsigned short Bs[128 * 64];
    int L = blockIdx.x;                      // 1280, NT=4
    int cc = L & 7, n = (L >> 3) & 3, g = L >> 5;
    int pi = cc + (g << 3);                  // [0,320)
    int e = pi / MT, m = pi % MT;
    int c = cnt[e]; c = c > CAP ? CAP : c;
    int m0 = m * 64;
    if (m0 >= c) return;
    int n0 = n * 128;
    const unsigned short* A = hbuf + ((size_t)e * CAP + m0) * HID;
    const unsigned short* B = w2t + ((size_t)e * DIM + n0) * HID;
    f32x4 z = {0.f, 0.f, 0.f, 0.f};
    f32x4 acc[2][4];
    #pragma unroll
    for (int mt = 0; mt < 2; mt++)
        #pragma unroll
        for (int nt = 0; nt < 4; nt++) acc[mt][nt] = z;
    mfma_main64<HID>(A, B, As, Bs, acc);
    int t = threadIdx.x;
    int wave = t >> 6, lane = t & 63;
    int wm = wave >> 1, wn = wave & 1, quad = lane >> 4, l16 = lane & 15;
    // hoist b2 per nt (4 reads instead of 32)
    float b2v[4];
    #pragma unroll
    for (int nt = 0; nt < 4; nt++)
        b2v[nt] = b2[e * DIM + n0 + wn * 64 + nt * 16 + l16];
    #pragma unroll
    for (int mt = 0; mt < 2; mt++) {
        #pragma unroll
        for (int r = 0; r < 4; r++) {
            int gm = m0 + wm * 32 + mt * 16 + quad * 4 + r;
            if (gm < c) {
                int si = sidx[e * CAP + gm];       // token*2 + slot
                float wgt = wtb[e * CAP + gm];
                unsigned short* yrow = ybuf + (size_t)si * DIM;
                #pragma unroll
                for (int nt = 0; nt < 4; nt++) {
                    int gn = n0 + wn * 64 + nt * 16 + l16;
                    yrow[gn] = f2bf(wgt * (acc[mt][nt][r] + b2v[nt]));
                }
            }
        }
    }
}

// out[n] = ybuf[n*2] + ybuf[n*2+1] (bf16 slots, fp32 sum+store).
__global__ void combine(const unsigned short* __restrict__ yb, float* __restrict__ out) {
    int i = blockIdx.x * 256 + threadIdx.x;   // over NTOK * DIM/8
    int n = i >> 6, d8 = i & 63;              // DIM/8 = 64
    us8 a = ((const us8*)(yb + (size_t)(2 * n) * DIM))[d8];
    us8 b = ((const us8*)(yb + (size_t)(2 * n + 1) * DIM))[d8];
    float4 o0, o1;
    o0.x = bf2f(a[0]) + bf2f(b[0]); o0.y = bf2f(a[1]) + bf2f(b[1]);
    o0.z = bf2f(a[2]) + bf2f(b[2]); o0.w = bf2f(a[3]) + bf2f(b[3]);
    o1.x = bf2f(a[4]) + bf2f(b[4]); o1.y = bf2f(a[5]) + bf2f(b[5]);
    o1.z = bf2f(a[6]) + bf2f(b[6]); o1.w = bf2f(a[7]) + bf2f(b[7]);
    float* op = out + (size_t)n * DIM + d8 * 8;
    *(float4*)op = o0;
    *(float4*)(op + 4) = o1;
}

extern "C" void kernel_launch(void* const* d_in, const int* in_sizes, int n_in,
                              void* d_out, int out_size, void* d_ws, size_t ws_size,
                              hipStream_t stream) {
    const float* x       = (const float*)d_in[0];
    const float* routing = (const float*)d_in[1];
    const float* W1      = (const float*)d_in[2];
    const float* b1      = (const float*)d_in[3];
    const float* W2      = (const float*)d_in[4];
    const float* b2      = (const float*)d_in[5];
    float* out = (float*)d_out;

    // workspace carve (ws poisoned 0xAA each call)
    char* w = (char*)d_ws;
    int*   cnt  = (int*)w;                                  // 256 B
    int*   sidx = (int*)(w + 256);                          // NE*CAP*4
    float* wtb  = (float*)(w + 256 + NE * CAP * 4);         // NE*CAP*4
    char* base = w + 256 + NE * CAP * 8;
    unsigned short* xg  = (unsigned short*)base;            // 20 MiB bf16 [NE][CAP][DIM]
    unsigned short* hb  = xg + (size_t)NE * CAP * DIM;      // 40 MiB bf16 [NE][CAP][HID]
    unsigned short* w1t = hb + (size_t)NE * CAP * HID;      // 16 MiB
    unsigned short* w2t = w1t + (size_t)NE * HID * DIM;     // 16 MiB
    unsigned short* ybuf = w2t + (size_t)NE * DIM * HID;    // 16 MiB bf16 [NTOK][2][DIM]

    hipMemsetAsync(cnt, 0, 256, stream);

    route_fill<<<NTOK / 256, 256, 0, stream>>>(routing, cnt, sidx, wtb);
    prep2<<<4096 + 5120, 256, 0, stream>>>(W1, W2, w1t, w2t, x, cnt, sidx, xg);

    gemm1_gelu<<<8 * MT * NE, 256, 0, stream>>>(xg, w1t, b1, cnt, hb);
    gemm2_store<<<4 * MT * NE, 256, 0, stream>>>(hb, w2t, b2, cnt, sidx, wtb, ybuf);
    combine<<<(NTOK * DIM / 8) / 256, 256, 0, stream>>>(ybuf, out);
}

// Round 11
// 219.967 us; speedup vs baseline: 1.2206x; 1.2206x over previous
//
#include <hip/hip_runtime.h>
#include <hip/hip_bf16.h>

#define NTOK 8192
#define DIM 512
#define HID 1024
#define NE 16
#define CAP 1280   // per-expert capacity; mean load = 1024, sigma ~30
#define MT 20      // m-tiles per expert (CAP/64)

typedef __attribute__((ext_vector_type(8))) short short8;
typedef __attribute__((ext_vector_type(8))) unsigned short us8;
typedef __attribute__((ext_vector_type(4))) float f32x4;

static __device__ __forceinline__ unsigned short f2bf(float f) {
    __hip_bfloat16 h = __float2bfloat16(f);
    return __builtin_bit_cast(unsigned short, h);
}
static __device__ __forceinline__ float bf2f(unsigned short u) {
    unsigned int v = (unsigned int)u << 16;
    return __builtin_bit_cast(float, v);
}

// async global->LDS, 16B per lane; LDS dst = wave-uniform base + lane*16.
// NOTE (R8 lesson): never place a dependent global_load->ds_write between
// gl_lds issue and the barrier -- the forced vmcnt(0) drains the async queue.
static __device__ __forceinline__ void gl_lds16(const unsigned short* g, unsigned short* l) {
    __builtin_amdgcn_global_load_lds(
        (const __attribute__((address_space(1))) unsigned int*)g,
        (__attribute__((address_space(3))) unsigned int*)l, 16, 0, 0);
}

// tanh-approx GELU; max |err| vs exact erf-GELU ~3e-3.
static __device__ __forceinline__ float gelu_f(float v) {
    float u = v * (0.7978845608f + 0.0356774081f * v * v);
    return v / (1.0f + __expf(-2.0f * u));
}

// LDS-aggregated routing: per-block local counts, 16 global atomics/block.
__global__ __launch_bounds__(256) void route_fill(const float* __restrict__ routing,
                                                  int* __restrict__ cnt,
                                                  int* __restrict__ sidx,
                                                  float* __restrict__ wtb) {
    __shared__ int lcnt[NE], lbase[NE];
    int t = threadIdx.x;
    int n = blockIdx.x * 256 + t;
    if (t < NE) lcnt[t] = 0;
    __syncthreads();
    int mye[2]; float myw[2]; int mypos[2]; int slot = 0;
    #pragma unroll
    for (int e = 0; e < NE; e++) {
        float r = routing[n * NE + e];
        if (r != 0.0f && slot < 2) {
            mye[slot] = e; myw[slot] = r;
            mypos[slot] = atomicAdd(&lcnt[e], 1);
            slot++;
        }
    }
    __syncthreads();
    if (t < NE) lbase[t] = atomicAdd(&cnt[t], lcnt[t]);
    __syncthreads();
    for (int s = 0; s < slot; s++) {
        int e = mye[s];
        int p = lbase[e] + mypos[s];
        if (p < CAP) { sidx[e * CAP + p] = n * 2 + s; wtb[e * CAP + p] = myw[s]; }
    }
}

// prep2: one big dispatch = weight transposes (blocks 0..4095) + token gather
// (blocks 4096..9215, 4 rows each).
__global__ __launch_bounds__(256) void prep2(const float* __restrict__ W1,
                                             const float* __restrict__ W2,
                                             unsigned short* __restrict__ w1t,
                                             unsigned short* __restrict__ w2t,
                                             const float* __restrict__ x,
                                             const int* __restrict__ cnt,
                                             const int* __restrict__ sidx,
                                             unsigned short* __restrict__ xg) {
    int b = blockIdx.x;
    int t = threadIdx.x;
    if (b < 4096) {
        __shared__ float tile[64][65];
        const float* src; unsigned short* dst; int R, C, bx, by;
        if (b < 2048) {               // W1: [DIM][HID], per-e tiles 16x8
            int e = b >> 7, rem = b & 127; bx = rem & 15; by = rem >> 4;
            R = DIM; C = HID;
            src = W1 + (size_t)e * R * C; dst = w1t + (size_t)e * R * C;
        } else {                      // W2: [HID][DIM], per-e tiles 8x16
            int bb = b - 2048;
            int e = bb >> 7, rem = bb & 127; bx = rem & 7; by = rem >> 3;
            R = HID; C = DIM;
            src = W2 + (size_t)e * R * C; dst = w2t + (size_t)e * R * C;
        }
        int c0 = bx * 64, r0 = by * 64;
        int tx = t & 15, ty = t >> 4;   // 16x16
        #pragma unroll
        for (int i = 0; i < 4; i++) {
            float4 v = *(const float4*)(src + (size_t)(r0 + ty + i * 16) * C + c0 + tx * 4);
            tile[ty + i * 16][tx * 4 + 0] = v.x;
            tile[ty + i * 16][tx * 4 + 1] = v.y;
            tile[ty + i * 16][tx * 4 + 2] = v.z;
            tile[ty + i * 16][tx * 4 + 3] = v.w;
        }
        __syncthreads();
        int seg = t & 7;                // 8 output segments of 8
        #pragma unroll
        for (int i = 0; i < 2; i++) {
            int dr = (t >> 3) + i * 32; // dst row (= source col)
            us8 o;
            #pragma unroll
            for (int j = 0; j < 8; j++)
                o[j] = f2bf(tile[seg * 8 + j][dr]);
            *(us8*)(dst + (size_t)(c0 + dr) * R + r0 + seg * 8) = o;
        }
    } else {
        // gather: 4 rows/block, 64 lanes/row, 16B us8 writes
        int gi = b - 4096;              // 0..5119
        int lane = t & 63, rl = t >> 6;
        int row = gi * 4 + rl;          // 0..20479 = e*CAP + r
        int e = row / CAP, r = row - e * CAP;
        int c = cnt[e]; c = c > CAP ? CAP : c;
        us8 o;
        if (r < c) {
            int n = sidx[row] >> 1;
            const float* xr = x + (size_t)n * DIM + lane * 8;
            float4 v0 = *(const float4*)xr;
            float4 v1 = *(const float4*)(xr + 4);
            o[0] = f2bf(v0.x); o[1] = f2bf(v0.y); o[2] = f2bf(v0.z); o[3] = f2bf(v0.w);
            o[4] = f2bf(v1.x); o[5] = f2bf(v1.y); o[6] = f2bf(v1.z); o[7] = f2bf(v1.w);
        } else {
            #pragma unroll
            for (int j = 0; j < 8; j++) o[j] = 0;
        }
        *(us8*)(xg + (size_t)row * DIM + lane * 8) = o;
    }
}

// 64x128 tile, BK=64, 4 waves (2x2): wave covers 32 rows x 64 cols,
// each wave 2x4 of 16x16x32 bf16 MFMA. A: MxK row-major, B: NxK row-major.
template <int K>
__device__ __forceinline__ void mfma_main64(const unsigned short* __restrict__ A,
                                            const unsigned short* __restrict__ B,
                                            unsigned short* As, unsigned short* Bs,
                                            f32x4 acc[2][4]) {
    int t = threadIdx.x;
    int wave = t >> 6, lane = t & 63;
    int wm = wave >> 1, wn = wave & 1;
    int quad = lane >> 4, l16 = lane & 15;
    int lr = lane >> 3;
    int col = (lane & 7) << 3;
    for (int kc = 0; kc < K; kc += 64) {
        __syncthreads();
        #pragma unroll
        for (int j = 0; j < 2; j++) {       // A: 64 rows
            int rb = wave * 16 + j * 8;
            gl_lds16(A + (size_t)(rb + lr) * K + kc + col, As + rb * 64);
        }
        #pragma unroll
        for (int j = 0; j < 4; j++) {       // B: 128 rows
            int rb = wave * 32 + j * 8;
            gl_lds16(B + (size_t)(rb + lr) * K + kc + col, Bs + rb * 64);
        }
        __syncthreads();
        #pragma unroll
        for (int kk = 0; kk < 64; kk += 32) {
            short8 av[2], bv[4];
            #pragma unroll
            for (int mt = 0; mt < 2; mt++)
                av[mt] = *(const short8*)(&As[(wm * 32 + mt * 16 + l16) * 64 + kk + quad * 8]);
            #pragma unroll
            for (int nt = 0; nt < 4; nt++)
                bv[nt] = *(const short8*)(&Bs[(wn * 64 + nt * 16 + l16) * 64 + kk + quad * 8]);
            #pragma unroll
            for (int mt = 0; mt < 2; mt++)
                #pragma unroll
                for (int nt = 0; nt < 4; nt++)
                    acc[mt][nt] = __builtin_amdgcn_mfma_f32_16x16x32_bf16(
                        av[mt], bv[nt], acc[mt][nt], 0, 0, 0);
        }
    }
}

// R5 swizzle (proven): all NT n-blocks of one (e,m) A-panel get flat ids
// congruent mod 8 -> A-sharers co-located per XCD; A fetched ~once/XCD.
// Occupancy NOTE (R10 lesson): 5 blocks/CU is the sweet spot; 6 blooms the
// concurrent L2 working set -> FETCH 78->122MB, WRITE 44->129MB, +26us.

__global__ __launch_bounds__(256, 5) void gemm1_gelu(
    const unsigned short* __restrict__ xg, const unsigned short* __restrict__ w1t,
    const float* __restrict__ b1, const int* __restrict__ cnt,
    unsigned short* __restrict__ hbuf) {
    __shared__ __align__(16) unsigned short As[64 * 64];
    __shared__ __align__(16) unsigned short Bs[128 * 64];
    int L = blockIdx.x;                      // 2560, NT=8
    int cc = L & 7, n = (L >> 3) & 7, g = L >> 6;
    int pi = cc + (g << 3);                  // [0,320)
    int e = pi / MT, m = pi % MT;
    int c = cnt[e]; c = c > CAP ? CAP : c;
    int m0 = m * 64;
    if (m0 >= c) return;
    int n0 = n * 128;
    const unsigned short* A = xg + ((size_t)e * CAP + m0) * DIM;
    const unsigned short* B = w1t + ((size_t)e * HID + n0) * DIM;
    f32x4 z = {0.f, 0.f, 0.f, 0.f};
    f32x4 acc[2][4];
    #pragma unroll
    for (int mt = 0; mt < 2; mt++)
        #pragma unroll
        for (int nt = 0; nt < 4; nt++) acc[mt][nt] = z;
    mfma_main64<DIM>(A, B, As, Bs, acc);
    int t = threadIdx.x;
    int wave = t >> 6, lane = t & 63;
    int wm = wave >> 1, wn = wave & 1, quad = lane >> 4, l16 = lane & 15;
    #pragma unroll
    for (int nt = 0; nt < 4; nt++) {
        int gn = n0 + wn * 64 + nt * 16 + l16;
        float bias = b1[e * HID + gn];
        #pragma unroll
        for (int mt = 0; mt < 2; mt++) {
            #pragma unroll
            for (int r = 0; r < 4; r++) {
                int gm = m0 + wm * 32 + mt * 16 + quad * 4 + r;
                float v = acc[mt][nt][r] + bias;
                hbuf[((size_t)e * CAP + gm) * HID + gn] = f2bf(gelu_f(v));
            }
        }
    }
}

__global__ __launch_bounds__(256, 5) void gemm2_store(
    const unsigned short* __restrict__ hbuf, const unsigned short* __restrict__ w2t,
    const float* __restrict__ b2, const int* __restrict__ cnt,
    const int* __restrict__ sidx, const float* __restrict__ wtb,
    unsigned short* __restrict__ ybuf) {
    __shared__ __align__(16) unsigned short As[64 * 64];
    __shared__ __align__(16) unsigned short Bs[128 * 64];
    int L = blockIdx.x;                      // 1280, NT=4
    int cc = L & 7, n = (L >> 3) & 3, g = L >> 5;
    int pi = cc + (g << 3);                  // [0,320)
    int e = pi / MT, m = pi % MT;
    int c = cnt[e]; c = c > CAP ? CAP : c;
    int m0 = m * 64;
    if (m0 >= c) return;
    int n0 = n * 128;
    const unsigned short* A = hbuf + ((size_t)e * CAP + m0) * HID;
    const unsigned short* B = w2t + ((size_t)e * DIM + n0) * HID;
    f32x4 z = {0.f, 0.f, 0.f, 0.f};
    f32x4 acc[2][4];
    #pragma unroll
    for (int mt = 0; mt < 2; mt++)
        #pragma unroll
        for (int nt = 0; nt < 4; nt++) acc[mt][nt] = z;
    mfma_main64<HID>(A, B, As, Bs, acc);
    int t = threadIdx.x;
    int wave = t >> 6, lane = t & 63;
    int wm = wave >> 1, wn = wave & 1, quad = lane >> 4, l16 = lane & 15;
    // hoist b2 per nt (4 reads instead of 32)
    float b2v[4];
    #pragma unroll
    for (int nt = 0; nt < 4; nt++)
        b2v[nt] = b2[e * DIM + n0 + wn * 64 + nt * 16 + l16];
    #pragma unroll
    for (int mt = 0; mt < 2; mt++) {
        #pragma unroll
        for (int r = 0; r < 4; r++) {
            int gm = m0 + wm * 32 + mt * 16 + quad * 4 + r;
            if (gm < c) {
                int si = sidx[e * CAP + gm];       // token*2 + slot
                float wgt = wtb[e * CAP + gm];
                unsigned short* yrow = ybuf + (size_t)si * DIM;
                #pragma unroll
                for (int nt = 0; nt < 4; nt++) {
                    int gn = n0 + wn * 64 + nt * 16 + l16;
                    yrow[gn] = f2bf(wgt * (acc[mt][nt][r] + b2v[nt]));
                }
            }
        }
    }
}

// out[n] = ybuf[n*2] + ybuf[n*2+1] (bf16 slots, fp32 sum+store).
__global__ void combine(const unsigned short* __restrict__ yb, float* __restrict__ out) {
    int i = blockIdx.x * 256 + threadIdx.x;   // over NTOK * DIM/8
    int n = i >> 6, d8 = i & 63;              // DIM/8 = 64
    us8 a = ((const us8*)(yb + (size_t)(2 * n) * DIM))[d8];
    us8 b = ((const us8*)(yb + (size_t)(2 * n + 1) * DIM))[d8];
    float4 o0, o1;
    o0.x = bf2f(a[0]) + bf2f(b[0]); o0.y = bf2f(a[1]) + bf2f(b[1]);
    o0.z = bf2f(a[2]) + bf2f(b[2]); o0.w = bf2f(a[3]) + bf2f(b[3]);
    o1.x = bf2f(a[4]) + bf2f(b[4]); o1.y = bf2f(a[5]) + bf2f(b[5]);
    o1.z = bf2f(a[6]) + bf2f(b[6]); o1.w = bf2f(a[7]) + bf2f(b[7]);
    float* op = out + (size_t)n * DIM + d8 * 8;
    *(float4*)op = o0;
    *(float4*)(op + 4) = o1;
}

extern "C" void kernel_launch(void* const* d_in, const int* in_sizes, int n_in,
                              void* d_out, int out_size, void* d_ws, size_t ws_size,
                              hipStream_t stream) {
    const float* x       = (const float*)d_in[0];
    const float* routing = (const float*)d_in[1];
    const float* W1      = (const float*)d_in[2];
    const float* b1      = (const float*)d_in[3];
    const float* W2      = (const float*)d_in[4];
    const float* b2      = (const float*)d_in[5];
    float* out = (float*)d_out;

    // workspace carve (ws poisoned 0xAA each call)
    char* w = (char*)d_ws;
    int*   cnt  = (int*)w;                                  // 256 B
    int*   sidx = (int*)(w + 256);                          // NE*CAP*4
    float* wtb  = (float*)(w + 256 + NE * CAP * 4);         // NE*CAP*4
    char* base = w + 256 + NE * CAP * 8;
    unsigned short* xg  = (unsigned short*)base;            // 20 MiB bf16 [NE][CAP][DIM]
    unsigned short* hb  = xg + (size_t)NE * CAP * DIM;      // 40 MiB bf16 [NE][CAP][HID]
    unsigned short* w1t = hb + (size_t)NE * CAP * HID;      // 16 MiB
    unsigned short* w2t = w1t + (size_t)NE * HID * DIM;     // 16 MiB
    unsigned short* ybuf = w2t + (size_t)NE * DIM * HID;    // 16 MiB bf16 [NTOK][2][DIM]

    hipMemsetAsync(cnt, 0, 256, stream);

    route_fill<<<NTOK / 256, 256, 0, stream>>>(routing, cnt, sidx, wtb);
    prep2<<<4096 + 5120, 256, 0, stream>>>(W1, W2, w1t, w2t, x, cnt, sidx, xg);

    gemm1_gelu<<<8 * MT * NE, 256, 0, stream>>>(xg, w1t, b1, cnt, hb);
    gemm2_store<<<4 * MT * NE, 256, 0, stream>>>(hb, w2t, b2, cnt, sidx, wtb, ybuf);
    combine<<<(NTOK * DIM / 8) / 256, 256, 0, stream>>>(ybuf, out);
}